// Round 1
// baseline (5772.528 us; speedup 1.0000x reference)
//
#include <hip/hip_runtime.h>
#include <hip/hip_bf16.h>

// GCN: 3x GCNConv (32->64->128->256) + global mean pool + linear(256->10)
// N=100000 nodes, E=800000 edges, G=512 graphs. All fp32.
//
// Workspace layout (floats):
//   dinv   : [0, 131072)                 (N used)
//   A      : [131072, 131072+25.6M)      h buffer (N*256 max)
//   B      : [A_end, +25.6M)             aggregated buffer
//   pooled : [B_end, +512*256)
//   counts : [pooled_end, +512)

#define NN 100000
#define NE 800000
#define NG 512

__global__ __launch_bounds__(256) void deg_count(const int* __restrict__ dst,
                                                 float* __restrict__ deg, int nE) {
    int e = blockIdx.x * 256 + threadIdx.x;
    if (e < nE) atomicAdd(&deg[dst[e]], 1.0f);
}

__global__ __launch_bounds__(256) void deg_finalize(float* __restrict__ deg, int n) {
    int i = blockIdx.x * 256 + threadIdx.x;
    if (i < n) deg[i] = rsqrtf(deg[i] + 1.0f);
}

// H[n, F] = X[n, K] @ W[K, F]   (optionally relu applied to X on load)
template <int K, int F, bool RELU>
__global__ __launch_bounds__(256) void gemm_kernel(const float* __restrict__ X,
                                                   const float* __restrict__ W,
                                                   float* __restrict__ H, int n) {
    constexpr int TPR = F / 4;        // threads per row
    constexpr int ROWS = 256 / TPR;   // rows per block
    __shared__ float xs[ROWS * K];
    const int row0 = blockIdx.x * ROWS;
    for (int i = threadIdx.x; i < ROWS * K; i += 256) {
        long long gi = (long long)row0 * K + i;
        float v = (gi < (long long)n * K) ? X[gi] : 0.0f;
        if (RELU) v = fmaxf(v, 0.0f);
        xs[i] = v;
    }
    __syncthreads();
    const int lr = threadIdx.x / TPR;
    const int cg = (threadIdx.x % TPR) * 4;
    const int row = row0 + lr;
    float4 acc = make_float4(0.f, 0.f, 0.f, 0.f);
#pragma unroll 8
    for (int k = 0; k < K; ++k) {
        const float xv = xs[lr * K + k];
        const float4 wv = *reinterpret_cast<const float4*>(&W[k * F + cg]);
        acc.x += xv * wv.x;
        acc.y += xv * wv.y;
        acc.z += xv * wv.z;
        acc.w += xv * wv.w;
    }
    if (row < n)
        *reinterpret_cast<float4*>(&H[(long long)row * F + cg]) = acc;
}

// out[i,:] = h[i,:] * dinv[i]^2 + b
template <int F>
__global__ __launch_bounds__(256) void self_init(const float* __restrict__ H,
                                                 const float* __restrict__ dinv,
                                                 const float* __restrict__ bias,
                                                 float* __restrict__ out, int n) {
    const int g = blockIdx.x * 256 + threadIdx.x;      // one float4 per thread
    const int total = n * (F / 4);
    if (g >= total) return;
    const int row = g / (F / 4);
    const int j = (g % (F / 4)) * 4;
    const float di = dinv[row];
    const float c = di * di;
    const float4 hv = *reinterpret_cast<const float4*>(&H[(long long)g * 4]);
    float4 o;
    o.x = hv.x * c + bias[j + 0];
    o.y = hv.y * c + bias[j + 1];
    o.z = hv.z * c + bias[j + 2];
    o.w = hv.w * c + bias[j + 3];
    *reinterpret_cast<float4*>(&out[(long long)g * 4]) = o;
}

// out[dst,:] += h[src,:] * dinv[src]*dinv[dst]  for each edge
template <int F>
__global__ __launch_bounds__(256) void edge_scatter(const float* __restrict__ H,
                                                    const int* __restrict__ ei,
                                                    const float* __restrict__ dinv,
                                                    float* __restrict__ out, int nE) {
    constexpr int TPE = F / 4;  // threads per edge
    const int g = blockIdx.x * 256 + threadIdx.x;
    const int e = g / TPE;
    const int j = (g % TPE) * 4;
    if (e >= nE) return;
    const int s = ei[e];
    const int d = ei[nE + e];
    const float coef = dinv[s] * dinv[d];
    const float4 hv = *reinterpret_cast<const float4*>(&H[(long long)s * F + j]);
    float* op = &out[(long long)d * F + j];
    atomicAdd(op + 0, hv.x * coef);
    atomicAdd(op + 1, hv.y * coef);
    atomicAdd(op + 2, hv.z * coef);
    atomicAdd(op + 3, hv.w * coef);
}

__global__ __launch_bounds__(256) void pool_count(const int* __restrict__ batch,
                                                  float* __restrict__ counts, int n) {
    int i = blockIdx.x * 256 + threadIdx.x;
    if (i < n) atomicAdd(&counts[batch[i]], 1.0f);
}

__global__ __launch_bounds__(256) void pool_sum(const float* __restrict__ a3,
                                                const int* __restrict__ batch,
                                                float* __restrict__ pooled, int n) {
    const int g = blockIdx.x * 256 + threadIdx.x;  // (node, j4)
    const int node = g / 64;                       // 256/4 = 64 float4 per node
    const int j = (g % 64) * 4;
    if (node >= n) return;
    const int b = batch[node];
    const float4 v = *reinterpret_cast<const float4*>(&a3[(long long)node * 256 + j]);
    float* p = &pooled[(long long)b * 256 + j];
    atomicAdd(p + 0, v.x);
    atomicAdd(p + 1, v.y);
    atomicAdd(p + 2, v.z);
    atomicAdd(p + 3, v.w);
}

// out[g, c] = sum_f (pooled[g,f]/max(cnt,1)) * Wlin[f,c] + blin[c]
__global__ __launch_bounds__(64) void final_linear(const float* __restrict__ pooled,
                                                   const float* __restrict__ counts,
                                                   const float* __restrict__ Wlin,
                                                   const float* __restrict__ blin,
                                                   float* __restrict__ out) {
    const int g = blockIdx.x;
    const int t = threadIdx.x;  // 64 threads
    const float inv = 1.0f / fmaxf(counts[g], 1.0f);
    float acc[10];
#pragma unroll
    for (int c = 0; c < 10; ++c) acc[c] = 0.f;
    for (int f = t; f < 256; f += 64) {
        const float v = pooled[g * 256 + f] * inv;
#pragma unroll
        for (int c = 0; c < 10; ++c) acc[c] += v * Wlin[f * 10 + c];
    }
#pragma unroll
    for (int c = 0; c < 10; ++c) {
        float a = acc[c];
        for (int off = 32; off > 0; off >>= 1) a += __shfl_down(a, off);
        if (t == 0) out[g * 10 + c] = a + blin[c];
    }
}

extern "C" void kernel_launch(void* const* d_in, const int* in_sizes, int n_in,
                              void* d_out, int out_size, void* d_ws, size_t ws_size,
                              hipStream_t stream) {
    const float* x    = (const float*)d_in[0];
    const int*   ei   = (const int*)d_in[1];   // [2, E]: row0=src, row1=dst
    const int*   batch = (const int*)d_in[2];
    const float* W1   = (const float*)d_in[3];
    const float* bc1  = (const float*)d_in[4];
    const float* W2   = (const float*)d_in[5];
    const float* bc2  = (const float*)d_in[6];
    const float* W3   = (const float*)d_in[7];
    const float* bc3  = (const float*)d_in[8];
    const float* Wlin = (const float*)d_in[9];
    const float* blin = (const float*)d_in[10];
    float* out = (float*)d_out;

    float* ws = (float*)d_ws;
    float* dinv   = ws;
    float* A      = ws + (1 << 17);           // 131072
    float* B      = A + (long long)NN * 256;
    float* pooled = B + (long long)NN * 256;
    float* counts = pooled + (long long)NG * 256;

    // ---- degree / dinv (shared by all 3 layers) ----
    hipMemsetAsync(dinv, 0, NN * sizeof(float), stream);
    deg_count<<<(NE + 255) / 256, 256, 0, stream>>>(ei + NE, dinv, NE);
    deg_finalize<<<(NN + 255) / 256, 256, 0, stream>>>(dinv, NN);

    // ---- layer 1: 32 -> 64 ----
    gemm_kernel<32, 64, false><<<(NN + 15) / 16, 256, 0, stream>>>(x, W1, A, NN);
    self_init<64><<<(NN * 16 + 255) / 256, 256, 0, stream>>>(A, dinv, bc1, B, NN);
    edge_scatter<64><<<(NE * 16 + 255) / 256, 256, 0, stream>>>(A, ei, dinv, B, NE);

    // ---- layer 2: 64 -> 128 (relu on input) ----
    gemm_kernel<64, 128, true><<<(NN + 7) / 8, 256, 0, stream>>>(B, W2, A, NN);
    self_init<128><<<(NN * 32 + 255) / 256, 256, 0, stream>>>(A, dinv, bc2, B, NN);
    edge_scatter<128><<<(NE * 32 + 255) / 256, 256, 0, stream>>>(A, ei, dinv, B, NE);

    // ---- layer 3: 128 -> 256 (relu on input, no relu after) ----
    gemm_kernel<128, 256, true><<<(NN + 3) / 4, 256, 0, stream>>>(B, W3, A, NN);
    self_init<256><<<(NN * 64 + 255) / 256, 256, 0, stream>>>(A, dinv, bc3, B, NN);
    edge_scatter<256><<<(NE * 64 + 255) / 256, 256, 0, stream>>>(A, ei, dinv, B, NE);

    // ---- global mean pool + linear ----
    hipMemsetAsync(pooled, 0, (NG * 256 + NG) * sizeof(float), stream);
    pool_count<<<(NN + 255) / 256, 256, 0, stream>>>(batch, counts, NN);
    pool_sum<<<(NN * 64 + 255) / 256, 256, 0, stream>>>(B, batch, pooled, NN);
    final_linear<<<NG, 64, 0, stream>>>(pooled, counts, Wlin, blin, out);
}

// Round 2
// 422.116 us; speedup vs baseline: 13.6752x; 13.6752x over previous
//
#include <hip/hip_runtime.h>
#include <hip/hip_bf16.h>

// GCN restructured:
//   a1 = Ahat x            (gather, F=32)
//   h1 = relu(a1@W1 + b1)  (N x 64)
//   a2 = Ahat h1           (gather, F=64)
//   h2 = relu(a2@W2 + b2)  (N x 128)
//   a3 = Ahat h2           (gather, F=128)
//   S  = segment_sum(a3)   (per-graph, width 128)
//   out = ((S@W3)/cnt + b3*(cnt/cnt_clip)) @ Wlin + blin
// Ahat aggregation done by CSR gather (no atomics in the hot path).

#define NN 100000
#define NE 800000
#define NG 512

// ---------------- degree ----------------
__global__ __launch_bounds__(256) void deg_count(const int* __restrict__ dst,
                                                 int* __restrict__ deg, int nE) {
    int e = blockIdx.x * 256 + threadIdx.x;
    if (e < nE) atomicAdd(&deg[dst[e]], 1);
}

__global__ __launch_bounds__(256) void deg_finalize(const int* __restrict__ deg,
                                                    float* __restrict__ dinv, int n) {
    int i = blockIdx.x * 256 + threadIdx.x;
    if (i < n) dinv[i] = rsqrtf((float)deg[i] + 1.0f);
}

// ---------------- exclusive scan of deg -> row_ptr (3 kernels) ----------------
// scanA: 1024 elems/block (4/thread), write per-elem exclusive-within-block + block sum
__global__ __launch_bounds__(256) void scanA(const int* __restrict__ deg,
                                             int* __restrict__ ex,
                                             int* __restrict__ bsum, int n) {
    __shared__ int sdata[256];
    const int t = threadIdx.x;
    const int base = blockIdx.x * 1024;
    const int idx = base + t * 4;
    int v[4];
#pragma unroll
    for (int k = 0; k < 4; ++k) v[k] = (idx + k < n) ? deg[idx + k] : 0;
    int ts = v[0] + v[1] + v[2] + v[3];
    sdata[t] = ts;
    __syncthreads();
    for (int off = 1; off < 256; off <<= 1) {
        int val = (t >= off) ? sdata[t - off] : 0;
        __syncthreads();
        sdata[t] += val;
        __syncthreads();
    }
    int run = sdata[t] - ts;  // exclusive prefix of this thread's chunk
    if (t == 255) bsum[blockIdx.x] = sdata[255];
#pragma unroll
    for (int k = 0; k < 4; ++k) {
        if (idx + k < n) ex[idx + k] = run;
        run += v[k];
    }
}

// scanB: exclusive scan of block sums (nb <= 128)
__global__ __launch_bounds__(128) void scanB(int* __restrict__ bsum, int nb) {
    __shared__ int s[128];
    const int t = threadIdx.x;
    int orig = (t < nb) ? bsum[t] : 0;
    s[t] = orig;
    __syncthreads();
    for (int off = 1; off < 128; off <<= 1) {
        int val = (t >= off) ? s[t - off] : 0;
        __syncthreads();
        s[t] += val;
        __syncthreads();
    }
    if (t < nb) bsum[t] = s[t] - orig;
}

// scanC: add block offsets (in place), copy to cursor, set row_ptr[n]=total
__global__ __launch_bounds__(256) void scanC(int* __restrict__ rp,
                                             const int* __restrict__ bsum,
                                             int* __restrict__ cursor, int n, int total) {
    int i = blockIdx.x * 256 + threadIdx.x;
    if (i < n) {
        int v = rp[i] + bsum[i >> 10];
        rp[i] = v;
        cursor[i] = v;
    }
    if (i == n) rp[n] = total;
}

// ---------------- CSR fill: cw[pos] = (src, weight) ----------------
__global__ __launch_bounds__(256) void fill_csr(const int* __restrict__ ei,
                                                const float* __restrict__ dinv,
                                                int* __restrict__ cursor,
                                                int2* __restrict__ cw, int nE) {
    int e = blockIdx.x * 256 + threadIdx.x;
    if (e >= nE) return;
    const int s = ei[e];
    const int d = ei[nE + e];
    const int pos = atomicAdd(&cursor[d], 1);
    const float wv = dinv[s] * dinv[d];
    cw[pos] = make_int2(s, __float_as_int(wv));
}

// ---------------- gather-aggregate: out[i] = h[i]*dinv[i]^2 + sum_e h[src]*w ----------------
template <int F>
__global__ __launch_bounds__(256) void gather(const float* __restrict__ H,
                                              const int* __restrict__ rp,
                                              const int2* __restrict__ cw,
                                              const float* __restrict__ dinv,
                                              float* __restrict__ out, int n) {
    constexpr int TPN = F / 4;
    const int g = blockIdx.x * 256 + threadIdx.x;
    const int node = g / TPN;
    const int j = (g % TPN) * 4;
    if (node >= n) return;
    const float di = dinv[node];
    const float c = di * di;
    const float4 sv = *reinterpret_cast<const float4*>(&H[(long long)node * F + j]);
    float4 acc = make_float4(sv.x * c, sv.y * c, sv.z * c, sv.w * c);
    float4 acc2 = make_float4(0.f, 0.f, 0.f, 0.f);
    int e = rp[node];
    const int end = rp[node + 1];
    for (; e + 2 <= end; e += 2) {
        const int2 c0 = cw[e];
        const int2 c1 = cw[e + 1];
        const float4 h0 = *reinterpret_cast<const float4*>(&H[(long long)c0.x * F + j]);
        const float4 h1 = *reinterpret_cast<const float4*>(&H[(long long)c1.x * F + j]);
        const float w0 = __int_as_float(c0.y);
        const float w1 = __int_as_float(c1.y);
        acc.x += h0.x * w0; acc.y += h0.y * w0; acc.z += h0.z * w0; acc.w += h0.w * w0;
        acc2.x += h1.x * w1; acc2.y += h1.y * w1; acc2.z += h1.z * w1; acc2.w += h1.w * w1;
    }
    if (e < end) {
        const int2 c0 = cw[e];
        const float4 h0 = *reinterpret_cast<const float4*>(&H[(long long)c0.x * F + j]);
        const float w0 = __int_as_float(c0.y);
        acc.x += h0.x * w0; acc.y += h0.y * w0; acc.z += h0.z * w0; acc.w += h0.w * w0;
    }
    acc.x += acc2.x; acc.y += acc2.y; acc.z += acc2.z; acc.w += acc2.w;
    *reinterpret_cast<float4*>(&out[(long long)node * F + j]) = acc;
}

// ---------------- H = relu?(X@W + b) ----------------
template <int K, int F, bool RELU_OUT>
__global__ __launch_bounds__(256) void gemm_bias(const float* __restrict__ X,
                                                 const float* __restrict__ W,
                                                 const float* __restrict__ bias,
                                                 float* __restrict__ H, int n) {
    constexpr int TPR = F / 4;       // threads per row
    constexpr int ROWS = 256 / TPR;  // rows per block
    __shared__ float xs[ROWS * K];
    const int row0 = blockIdx.x * ROWS;
    for (int i = threadIdx.x; i < ROWS * K; i += 256) {
        long long gi = (long long)row0 * K + i;
        xs[i] = (gi < (long long)n * K) ? X[gi] : 0.0f;
    }
    __syncthreads();
    const int lr = threadIdx.x / TPR;
    const int cg = (threadIdx.x % TPR) * 4;
    const int row = row0 + lr;
    float4 acc = make_float4(0.f, 0.f, 0.f, 0.f);
#pragma unroll 8
    for (int k = 0; k < K; ++k) {
        const float xv = xs[lr * K + k];
        const float4 wv = *reinterpret_cast<const float4*>(&W[k * F + cg]);
        acc.x += xv * wv.x;
        acc.y += xv * wv.y;
        acc.z += xv * wv.z;
        acc.w += xv * wv.w;
    }
    const float4 bv = *reinterpret_cast<const float4*>(&bias[cg]);
    acc.x += bv.x; acc.y += bv.y; acc.z += bv.z; acc.w += bv.w;
    if (RELU_OUT) {
        acc.x = fmaxf(acc.x, 0.f); acc.y = fmaxf(acc.y, 0.f);
        acc.z = fmaxf(acc.z, 0.f); acc.w = fmaxf(acc.w, 0.f);
    }
    if (row < n)
        *reinterpret_cast<float4*>(&H[(long long)row * F + cg]) = acc;
}

// ---------------- per-graph segment sum of a3 (width 128), batch sorted ----------------
__device__ __forceinline__ int lower_bound_i(const int* __restrict__ a, int n, int key) {
    int lo = 0, hi = n;
    while (lo < hi) {
        int mid = (lo + hi) >> 1;
        if (a[mid] < key) lo = mid + 1; else hi = mid;
    }
    return lo;
}

__global__ __launch_bounds__(128) void pool_graph(const float* __restrict__ a3,
                                                  const int* __restrict__ batch,
                                                  float* __restrict__ S,
                                                  float* __restrict__ counts, int n) {
    const int g = blockIdx.x;
    const int f = threadIdx.x;
    const int start = lower_bound_i(batch, n, g);
    const int end = lower_bound_i(batch, n, g + 1);
    float acc = 0.f;
    for (int node = start; node < end; ++node) acc += a3[(long long)node * 128 + f];
    S[g * 128 + f] = acc;
    if (f == 0) counts[g] = (float)(end - start);
}

// ---------------- final: out[g] = ((S@W3)*inv + b3*bscale) @ Wlin + blin ----------------
__global__ __launch_bounds__(256) void final_k(const float* __restrict__ S,
                                               const float* __restrict__ counts,
                                               const float* __restrict__ W3,
                                               const float* __restrict__ b3,
                                               const float* __restrict__ Wlin,
                                               const float* __restrict__ blin,
                                               float* __restrict__ out) {
    __shared__ float srow[128];
    __shared__ float prow[256];
    const int g = blockIdx.x;
    const int t = threadIdx.x;
    if (t < 128) srow[t] = S[g * 128 + t];
    __syncthreads();
    const float cnt = counts[g];
    const float inv = 1.0f / fmaxf(cnt, 1.0f);
    const float bscale = cnt * inv;  // 0 if empty graph, else 1
    float p = 0.f;
    for (int k = 0; k < 128; ++k) p += srow[k] * W3[k * 256 + t];
    prow[t] = p * inv + b3[t] * bscale;
    __syncthreads();
    if (t < 10) {
        float a = blin[t];
        for (int f = 0; f < 256; ++f) a += prow[f] * Wlin[f * 10 + t];
        out[g * 10 + t] = a;
    }
}

extern "C" void kernel_launch(void* const* d_in, const int* in_sizes, int n_in,
                              void* d_out, int out_size, void* d_ws, size_t ws_size,
                              hipStream_t stream) {
    const float* x     = (const float*)d_in[0];
    const int*   ei    = (const int*)d_in[1];   // [2,E]: row0=src, row1=dst
    const int*   batch = (const int*)d_in[2];
    const float* W1    = (const float*)d_in[3];
    const float* bc1   = (const float*)d_in[4];
    const float* W2    = (const float*)d_in[5];
    const float* bc2   = (const float*)d_in[6];
    const float* W3    = (const float*)d_in[7];
    const float* bc3   = (const float*)d_in[8];
    const float* Wlin  = (const float*)d_in[9];
    const float* blin  = (const float*)d_in[10];
    float* out = (float*)d_out;

    // -------- workspace carve-up (16B aligned regions) --------
    char* w = (char*)d_ws;
    int*   deg    = (int*)w;               w += 131072 * 4;
    int*   rp     = (int*)w;               w += 131072 * 4;   // row_ptr[N+1]
    int*   cursor = (int*)w;               w += 131072 * 4;
    int*   bsum   = (int*)w;               w += 256 * 4;
    float* dinv   = (float*)w;             w += 131072 * 4;
    int2*  cw     = (int2*)w;              w += (long long)NE * 8;
    float* P      = (float*)w;             w += (long long)NN * 128 * 4;
    float* Q      = (float*)w;             w += (long long)NN * 128 * 4;
    float* S      = (float*)w;             w += NG * 128 * 4;
    float* counts = (float*)w;             w += NG * 4;

    const int nbScanA = (NN + 1023) / 1024;  // 98 (must be <= 128 for scanB)

    // -------- degree + dinv + CSR --------
    hipMemsetAsync(deg, 0, NN * sizeof(int), stream);
    deg_count<<<(NE + 255) / 256, 256, 0, stream>>>(ei + NE, deg, NE);
    scanA<<<nbScanA, 256, 0, stream>>>(deg, rp, bsum, NN);
    scanB<<<1, 128, 0, stream>>>(bsum, nbScanA);
    scanC<<<(NN + 256) / 256, 256, 0, stream>>>(rp, bsum, cursor, NN, NE);
    deg_finalize<<<(NN + 255) / 256, 256, 0, stream>>>(deg, dinv, NN);
    fill_csr<<<(NE + 255) / 256, 256, 0, stream>>>(ei, dinv, cursor, cw, NE);

    // -------- layer 1: a1 = Ahat x (F=32); h1 = relu(a1@W1+b1) --------
    gather<32><<<(NN * 8 + 255) / 256, 256, 0, stream>>>(x, rp, cw, dinv, P, NN);
    gemm_bias<32, 64, true><<<(NN + 15) / 16, 256, 0, stream>>>(P, W1, bc1, Q, NN);

    // -------- layer 2: a2 = Ahat h1 (F=64); h2 = relu(a2@W2+b2) --------
    gather<64><<<(NN * 16 + 255) / 256, 256, 0, stream>>>(Q, rp, cw, dinv, P, NN);
    gemm_bias<64, 128, true><<<(NN + 7) / 8, 256, 0, stream>>>(P, W2, bc2, Q, NN);

    // -------- layer 3 aggregation only: a3 = Ahat h2 (F=128) --------
    gather<128><<<(NN * 32 + 255) / 256, 256, 0, stream>>>(Q, rp, cw, dinv, P, NN);

    // -------- pool (sum a3 per graph) + fused last GEMM / mean / linear --------
    pool_graph<<<NG, 128, 0, stream>>>(P, batch, S, counts, NN);
    final_k<<<NG, 256, 0, stream>>>(S, counts, W3, bc3, Wlin, blin, out);
}

// Round 3
// 293.225 us; speedup vs baseline: 19.6863x; 1.4396x over previous
//
#include <hip/hip_runtime.h>
#include <hip/hip_bf16.h>

// GCN restructured + fused:
//   h1 = relu((Ahat x) @ W1 + b1)   -- fused gather+GEMM, K=32 -> F=64
//   h2 = relu((Ahat h1) @ W2 + b2)  -- fused gather+GEMM, K=64 -> F=128
//   a3 = Ahat h2                    -- gather, F=128
//   S  = segment_sum(a3), counts    -- per-graph pool (batch sorted)
//   out = ((S@W3)/cnt + b3) @ Wlin + blin  -- tiny fused final
// CSR built per call (deg -> scan -> atomic-cursor fill).

#define NN 100000
#define NE 800000
#define NG 512

// ---------------- degree ----------------
__global__ __launch_bounds__(256) void deg_count(const int* __restrict__ dst,
                                                 int* __restrict__ deg, int nE) {
    int e = blockIdx.x * 256 + threadIdx.x;
    if (e < nE) atomicAdd(&deg[dst[e]], 1);
}

__global__ __launch_bounds__(256) void deg_finalize(const int* __restrict__ deg,
                                                    float* __restrict__ dinv, int n) {
    int i = blockIdx.x * 256 + threadIdx.x;
    if (i < n) dinv[i] = rsqrtf((float)deg[i] + 1.0f);
}

// ---------------- exclusive scan of deg -> row_ptr ----------------
__global__ __launch_bounds__(256) void scanA(const int* __restrict__ deg,
                                             int* __restrict__ ex,
                                             int* __restrict__ bsum, int n) {
    __shared__ int sdata[256];
    const int t = threadIdx.x;
    const int base = blockIdx.x * 1024;
    const int idx = base + t * 4;
    int v[4];
#pragma unroll
    for (int k = 0; k < 4; ++k) v[k] = (idx + k < n) ? deg[idx + k] : 0;
    int ts = v[0] + v[1] + v[2] + v[3];
    sdata[t] = ts;
    __syncthreads();
    for (int off = 1; off < 256; off <<= 1) {
        int val = (t >= off) ? sdata[t - off] : 0;
        __syncthreads();
        sdata[t] += val;
        __syncthreads();
    }
    int run = sdata[t] - ts;
    if (t == 255) bsum[blockIdx.x] = sdata[255];
#pragma unroll
    for (int k = 0; k < 4; ++k) {
        if (idx + k < n) ex[idx + k] = run;
        run += v[k];
    }
}

__global__ __launch_bounds__(128) void scanB(int* __restrict__ bsum, int nb) {
    __shared__ int s[128];
    const int t = threadIdx.x;
    int orig = (t < nb) ? bsum[t] : 0;
    s[t] = orig;
    __syncthreads();
    for (int off = 1; off < 128; off <<= 1) {
        int val = (t >= off) ? s[t - off] : 0;
        __syncthreads();
        s[t] += val;
        __syncthreads();
    }
    if (t < nb) bsum[t] = s[t] - orig;
}

__global__ __launch_bounds__(256) void scanC(int* __restrict__ rp,
                                             const int* __restrict__ bsum,
                                             int* __restrict__ cursor, int n, int total) {
    int i = blockIdx.x * 256 + threadIdx.x;
    if (i < n) {
        int v = rp[i] + bsum[i >> 10];
        rp[i] = v;
        cursor[i] = v;
    }
    if (i == n) rp[n] = total;
}

// ---------------- CSR fill: cw[pos] = (src, weight) ----------------
__global__ __launch_bounds__(256) void fill_csr(const int* __restrict__ ei,
                                                const float* __restrict__ dinv,
                                                int* __restrict__ cursor,
                                                int2* __restrict__ cw, int nE) {
    int e = blockIdx.x * 256 + threadIdx.x;
    if (e >= nE) return;
    const int s = ei[e];
    const int d = ei[nE + e];
    const int pos = atomicAdd(&cursor[d], 1);
    const float wv = dinv[s] * dinv[d];
    cw[pos] = make_int2(s, __float_as_int(wv));
}

// ---------------- fused: out = relu?((Ahat X) @ W + b), per-block NODES rows ----
// Phase A: aggregate NODES rows of width K into LDS. Phase B: register-tiled GEMM
// with W staged in LDS (2 rows x 4 cols per thread).
template <int K, int F, int NODES, bool RELU_OUT>
__global__ __launch_bounds__(256) void gather_gemm(const float* __restrict__ X,
                                                   const int* __restrict__ rp,
                                                   const int2* __restrict__ cw,
                                                   const float* __restrict__ dinv,
                                                   const float* __restrict__ W,
                                                   const float* __restrict__ bias,
                                                   float* __restrict__ out, int n) {
    constexpr int TPN = K / 4;         // threads per node (phase A)
    static_assert(256 / TPN == NODES, "node count mismatch");
    constexpr int AS = K + 4;          // padded agg stride (keeps float4 align, spreads banks)
    __shared__ float agg[NODES * AS];
    __shared__ float Wl[K * F];

    // stage W (float4)
    for (int i = threadIdx.x; i < K * F / 4; i += 256)
        *reinterpret_cast<float4*>(&Wl[i * 4]) =
            *reinterpret_cast<const float4*>(&W[i * 4]);

    // ---- phase A: gather-aggregate into LDS ----
    const int nl = threadIdx.x / TPN;
    const int j = (threadIdx.x % TPN) * 4;
    const int node = blockIdx.x * NODES + nl;
    float4 acc = make_float4(0.f, 0.f, 0.f, 0.f);
    float4 acc2 = make_float4(0.f, 0.f, 0.f, 0.f);
    if (node < n) {
        const float di = dinv[node];
        const float c = di * di;
        const float4 sv = *reinterpret_cast<const float4*>(&X[(long long)node * K + j]);
        acc.x = sv.x * c; acc.y = sv.y * c; acc.z = sv.z * c; acc.w = sv.w * c;
        int e = rp[node];
        const int end = rp[node + 1];
        for (; e + 2 <= end; e += 2) {
            const int2 c0 = cw[e];
            const int2 c1 = cw[e + 1];
            const float4 h0 = *reinterpret_cast<const float4*>(&X[(long long)c0.x * K + j]);
            const float4 h1 = *reinterpret_cast<const float4*>(&X[(long long)c1.x * K + j]);
            const float w0 = __int_as_float(c0.y);
            const float w1 = __int_as_float(c1.y);
            acc.x += h0.x * w0; acc.y += h0.y * w0; acc.z += h0.z * w0; acc.w += h0.w * w0;
            acc2.x += h1.x * w1; acc2.y += h1.y * w1; acc2.z += h1.z * w1; acc2.w += h1.w * w1;
        }
        if (e < end) {
            const int2 c0 = cw[e];
            const float4 h0 = *reinterpret_cast<const float4*>(&X[(long long)c0.x * K + j]);
            const float w0 = __int_as_float(c0.y);
            acc.x += h0.x * w0; acc.y += h0.y * w0; acc.z += h0.z * w0; acc.w += h0.w * w0;
        }
        acc.x += acc2.x; acc.y += acc2.y; acc.z += acc2.z; acc.w += acc2.w;
    }
    *reinterpret_cast<float4*>(&agg[nl * AS + j]) = acc;
    __syncthreads();

    // ---- phase B: [NODES x K] @ [K x F], 2 rows x 4 cols per thread ----
    constexpr int CG = F / 4;           // col groups
    static_assert(NODES * CG == 2 * 256, "tile mismatch");
    const int r0 = (threadIdx.x / CG) * 2;
    const int cg = (threadIdx.x % CG) * 4;
    float4 o0 = make_float4(0.f, 0.f, 0.f, 0.f);
    float4 o1 = make_float4(0.f, 0.f, 0.f, 0.f);
#pragma unroll 8
    for (int k = 0; k < K; ++k) {
        const float4 wv = *reinterpret_cast<const float4*>(&Wl[k * F + cg]);
        const float x0 = agg[r0 * AS + k];
        const float x1 = agg[(r0 + 1) * AS + k];
        o0.x += x0 * wv.x; o0.y += x0 * wv.y; o0.z += x0 * wv.z; o0.w += x0 * wv.w;
        o1.x += x1 * wv.x; o1.y += x1 * wv.y; o1.z += x1 * wv.z; o1.w += x1 * wv.w;
    }
    const float4 bv = *reinterpret_cast<const float4*>(&bias[cg]);
    o0.x += bv.x; o0.y += bv.y; o0.z += bv.z; o0.w += bv.w;
    o1.x += bv.x; o1.y += bv.y; o1.z += bv.z; o1.w += bv.w;
    if (RELU_OUT) {
        o0.x = fmaxf(o0.x, 0.f); o0.y = fmaxf(o0.y, 0.f);
        o0.z = fmaxf(o0.z, 0.f); o0.w = fmaxf(o0.w, 0.f);
        o1.x = fmaxf(o1.x, 0.f); o1.y = fmaxf(o1.y, 0.f);
        o1.z = fmaxf(o1.z, 0.f); o1.w = fmaxf(o1.w, 0.f);
    }
    const int row0 = blockIdx.x * NODES + r0;
    if (row0 < n)
        *reinterpret_cast<float4*>(&out[(long long)row0 * F + cg]) = o0;
    if (row0 + 1 < n)
        *reinterpret_cast<float4*>(&out[(long long)(row0 + 1) * F + cg]) = o1;
}

// ---------------- gather-aggregate only (layer 3, F=128) ----------------
template <int F>
__global__ __launch_bounds__(256) void gather(const float* __restrict__ H,
                                              const int* __restrict__ rp,
                                              const int2* __restrict__ cw,
                                              const float* __restrict__ dinv,
                                              float* __restrict__ out, int n) {
    constexpr int TPN = F / 4;
    const int g = blockIdx.x * 256 + threadIdx.x;
    const int node = g / TPN;
    const int j = (g % TPN) * 4;
    if (node >= n) return;
    const float di = dinv[node];
    const float c = di * di;
    const float4 sv = *reinterpret_cast<const float4*>(&H[(long long)node * F + j]);
    float4 acc = make_float4(sv.x * c, sv.y * c, sv.z * c, sv.w * c);
    float4 acc2 = make_float4(0.f, 0.f, 0.f, 0.f);
    int e = rp[node];
    const int end = rp[node + 1];
    for (; e + 2 <= end; e += 2) {
        const int2 c0 = cw[e];
        const int2 c1 = cw[e + 1];
        const float4 h0 = *reinterpret_cast<const float4*>(&H[(long long)c0.x * F + j]);
        const float4 h1 = *reinterpret_cast<const float4*>(&H[(long long)c1.x * F + j]);
        const float w0 = __int_as_float(c0.y);
        const float w1 = __int_as_float(c1.y);
        acc.x += h0.x * w0; acc.y += h0.y * w0; acc.z += h0.z * w0; acc.w += h0.w * w0;
        acc2.x += h1.x * w1; acc2.y += h1.y * w1; acc2.z += h1.z * w1; acc2.w += h1.w * w1;
    }
    if (e < end) {
        const int2 c0 = cw[e];
        const float4 h0 = *reinterpret_cast<const float4*>(&H[(long long)c0.x * F + j]);
        const float w0 = __int_as_float(c0.y);
        acc.x += h0.x * w0; acc.y += h0.y * w0; acc.z += h0.z * w0; acc.w += h0.w * w0;
    }
    acc.x += acc2.x; acc.y += acc2.y; acc.z += acc2.z; acc.w += acc2.w;
    *reinterpret_cast<float4*>(&out[(long long)node * F + j]) = acc;
}

// ---------------- per-graph segment sum of a3 (width 128), batch sorted ------
__device__ __forceinline__ int lower_bound_i(const int* __restrict__ a, int n, int key) {
    int lo = 0, hi = n;
    while (lo < hi) {
        int mid = (lo + hi) >> 1;
        if (a[mid] < key) lo = mid + 1; else hi = mid;
    }
    return lo;
}

__global__ __launch_bounds__(256) void pool_graph(const float* __restrict__ a3,
                                                  const int* __restrict__ batch,
                                                  float* __restrict__ S,
                                                  float* __restrict__ counts, int n) {
    __shared__ float red[8 * 128];
    const int g = blockIdx.x;
    const int t = threadIdx.x;
    const int slot = t >> 5;          // 8 row slots
    const int f4 = (t & 31) * 4;
    const int start = lower_bound_i(batch, n, g);
    const int end = lower_bound_i(batch, n, g + 1);
    float4 acc = make_float4(0.f, 0.f, 0.f, 0.f);
    for (int node = start + slot; node < end; node += 8) {
        const float4 v = *reinterpret_cast<const float4*>(&a3[(long long)node * 128 + f4]);
        acc.x += v.x; acc.y += v.y; acc.z += v.z; acc.w += v.w;
    }
    *reinterpret_cast<float4*>(&red[slot * 128 + f4]) = acc;
    __syncthreads();
    if (t < 128) {
        float s = 0.f;
#pragma unroll
        for (int sl = 0; sl < 8; ++sl) s += red[sl * 128 + t];
        S[g * 128 + t] = s;
    }
    if (t == 0) counts[g] = (float)(end - start);
}

// ---------------- final: out[g] = ((S@W3)*inv + b3*bscale) @ Wlin + blin -----
__global__ __launch_bounds__(256) void final_k(const float* __restrict__ S,
                                               const float* __restrict__ counts,
                                               const float* __restrict__ W3,
                                               const float* __restrict__ b3,
                                               const float* __restrict__ Wlin,
                                               const float* __restrict__ blin,
                                               float* __restrict__ out) {
    __shared__ float srow[128];
    __shared__ float prow[256];
    const int g = blockIdx.x;
    const int t = threadIdx.x;
    if (t < 128) srow[t] = S[g * 128 + t];
    __syncthreads();
    const float cnt = counts[g];
    const float inv = 1.0f / fmaxf(cnt, 1.0f);
    const float bscale = cnt * inv;
    float p = 0.f;
    for (int k = 0; k < 128; ++k) p += srow[k] * W3[k * 256 + t];
    prow[t] = p * inv + b3[t] * bscale;
    __syncthreads();
    if (t < 10) {
        float a = blin[t];
        for (int f = 0; f < 256; ++f) a += prow[f] * Wlin[f * 10 + t];
        out[g * 10 + t] = a;
    }
}

extern "C" void kernel_launch(void* const* d_in, const int* in_sizes, int n_in,
                              void* d_out, int out_size, void* d_ws, size_t ws_size,
                              hipStream_t stream) {
    const float* x     = (const float*)d_in[0];
    const int*   ei    = (const int*)d_in[1];   // [2,E]: row0=src, row1=dst
    const int*   batch = (const int*)d_in[2];
    const float* W1    = (const float*)d_in[3];
    const float* bc1   = (const float*)d_in[4];
    const float* W2    = (const float*)d_in[5];
    const float* bc2   = (const float*)d_in[6];
    const float* W3    = (const float*)d_in[7];
    const float* bc3   = (const float*)d_in[8];
    const float* Wlin  = (const float*)d_in[9];
    const float* blin  = (const float*)d_in[10];
    float* out = (float*)d_out;

    char* w = (char*)d_ws;
    int*   deg    = (int*)w;               w += 131072 * 4;
    int*   rp     = (int*)w;               w += 131072 * 4;   // row_ptr[N+1]
    int*   cursor = (int*)w;               w += 131072 * 4;
    int*   bsum   = (int*)w;               w += 256 * 4;
    float* dinv   = (float*)w;             w += 131072 * 4;
    int2*  cw     = (int2*)w;              w += (long long)NE * 8;
    float* P      = (float*)w;             w += (long long)NN * 128 * 4;  // h2 / scratch
    float* Q      = (float*)w;             w += (long long)NN * 128 * 4;  // h1 / a3
    float* S      = (float*)w;             w += NG * 128 * 4;
    float* counts = (float*)w;             w += NG * 4;

    const int nbScanA = (NN + 1023) / 1024;  // 98 <= 128

    // -------- degree + dinv + CSR --------
    hipMemsetAsync(deg, 0, NN * sizeof(int), stream);
    deg_count<<<(NE + 255) / 256, 256, 0, stream>>>(ei + NE, deg, NE);
    scanA<<<nbScanA, 256, 0, stream>>>(deg, rp, bsum, NN);
    scanB<<<1, 128, 0, stream>>>(bsum, nbScanA);
    scanC<<<(NN + 256) / 256, 256, 0, stream>>>(rp, bsum, cursor, NN, NE);
    deg_finalize<<<(NN + 255) / 256, 256, 0, stream>>>(deg, dinv, NN);
    fill_csr<<<(NE + 255) / 256, 256, 0, stream>>>(ei, dinv, cursor, cw, NE);

    // -------- layer 1 fused: h1 = relu((Ahat x)@W1 + b1) --------
    gather_gemm<32, 64, 32, true><<<(NN + 31) / 32, 256, 0, stream>>>(
        x, rp, cw, dinv, W1, bc1, Q, NN);

    // -------- layer 2 fused: h2 = relu((Ahat h1)@W2 + b2) --------
    gather_gemm<64, 128, 16, true><<<(NN + 15) / 16, 256, 0, stream>>>(
        Q, rp, cw, dinv, W2, bc2, P, NN);

    // -------- layer 3 aggregation: a3 = Ahat h2 --------
    gather<128><<<(NN * 32 + 255) / 256, 256, 0, stream>>>(P, rp, cw, dinv, Q, NN);

    // -------- pool + fused final --------
    pool_graph<<<NG, 256, 0, stream>>>(Q, batch, S, counts, NN);
    final_k<<<NG, 256, 0, stream>>>(S, counts, W3, bc3, Wlin, blin, out);
}

// Round 4
// 286.977 us; speedup vs baseline: 20.1149x; 1.0218x over previous
//
#include <hip/hip_runtime.h>
#include <hip/hip_bf16.h>

// GCN restructured + fused:
//   h1 = relu((Ahat x) @ W1 + b1)   -- fused gather+GEMM, K=32 -> F=64
//   h2 = relu((Ahat h1) @ W2 + b2)  -- fused gather+GEMM, K=64 -> F=128
//   Spart = per-graph partial segment sums of (Ahat h2)   -- fused gather+pool
//   out = ((sum(Spart)@W3)/cnt + b3) @ Wlin + blin
// CSR built per call (deg -> scan -> atomic-cursor fill). No atomics in hot path.

#define NN 100000
#define NE 800000
#define NG 512
#define PARTS 4   // partial blocks per graph in gather_pool

// ---------------- degree ----------------
__global__ __launch_bounds__(256) void deg_count(const int* __restrict__ dst,
                                                 int* __restrict__ deg, int nE) {
    int e = blockIdx.x * 256 + threadIdx.x;
    if (e < nE) atomicAdd(&deg[dst[e]], 1);
}

// ---------------- exclusive scan of deg -> row_ptr ----------------
__global__ __launch_bounds__(256) void scanA(const int* __restrict__ deg,
                                             int* __restrict__ ex,
                                             int* __restrict__ bsum, int n) {
    __shared__ int sdata[256];
    const int t = threadIdx.x;
    const int base = blockIdx.x * 1024;
    const int idx = base + t * 4;
    int v[4];
#pragma unroll
    for (int k = 0; k < 4; ++k) v[k] = (idx + k < n) ? deg[idx + k] : 0;
    int ts = v[0] + v[1] + v[2] + v[3];
    sdata[t] = ts;
    __syncthreads();
    for (int off = 1; off < 256; off <<= 1) {
        int val = (t >= off) ? sdata[t - off] : 0;
        __syncthreads();
        sdata[t] += val;
        __syncthreads();
    }
    int run = sdata[t] - ts;
    if (t == 255) bsum[blockIdx.x] = sdata[255];
#pragma unroll
    for (int k = 0; k < 4; ++k) {
        if (idx + k < n) ex[idx + k] = run;
        run += v[k];
    }
}

__global__ __launch_bounds__(128) void scanB(int* __restrict__ bsum, int nb) {
    __shared__ int s[128];
    const int t = threadIdx.x;
    int orig = (t < nb) ? bsum[t] : 0;
    s[t] = orig;
    __syncthreads();
    for (int off = 1; off < 128; off <<= 1) {
        int val = (t >= off) ? s[t - off] : 0;
        __syncthreads();
        s[t] += val;
        __syncthreads();
    }
    if (t < nb) bsum[t] = s[t] - orig;
}

// scanC: finalize row_ptr + cursor copy + dinv = rsqrt(deg+1)
__global__ __launch_bounds__(256) void scanC(int* __restrict__ rp,
                                             const int* __restrict__ bsum,
                                             int* __restrict__ cursor,
                                             const int* __restrict__ deg,
                                             float* __restrict__ dinv,
                                             int n, int total) {
    int i = blockIdx.x * 256 + threadIdx.x;
    if (i < n) {
        int v = rp[i] + bsum[i >> 10];
        rp[i] = v;
        cursor[i] = v;
        dinv[i] = rsqrtf((float)deg[i] + 1.0f);
    }
    if (i == n) rp[n] = total;
}

// ---------------- CSR fill: cw[pos] = (src, weight) ----------------
__global__ __launch_bounds__(256) void fill_csr(const int* __restrict__ ei,
                                                const float* __restrict__ dinv,
                                                int* __restrict__ cursor,
                                                int2* __restrict__ cw, int nE) {
    int e = blockIdx.x * 256 + threadIdx.x;
    if (e >= nE) return;
    const int s = ei[e];
    const int d = ei[nE + e];
    const int pos = atomicAdd(&cursor[d], 1);
    const float wv = dinv[s] * dinv[d];
    cw[pos] = make_int2(s, __float_as_int(wv));
}

// ---------------- fused: out = relu((Ahat X) @ W + b) ----------------
// Phase A: aggregate NODES rows of width K into LDS (gather via CSR).
// Phase B: [NODES x K] @ [K x F] with W read from global (L1-broadcast),
//          2 rows x 4 cols per thread. Low LDS -> high occupancy.
template <int K, int F, int NODES, bool RELU_OUT>
__global__ __launch_bounds__(256) void gather_gemm(const float* __restrict__ X,
                                                   const int* __restrict__ rp,
                                                   const int2* __restrict__ cw,
                                                   const float* __restrict__ dinv,
                                                   const float* __restrict__ W,
                                                   const float* __restrict__ bias,
                                                   float* __restrict__ out, int n) {
    constexpr int TPN = K / 4;         // threads per node (phase A)
    static_assert(256 / TPN == NODES, "node count mismatch");
    constexpr int AS = K + 4;          // padded agg stride
    __shared__ float agg[NODES * AS];

    // ---- phase A: gather-aggregate into LDS ----
    const int nl = threadIdx.x / TPN;
    const int j = (threadIdx.x % TPN) * 4;
    const int node = blockIdx.x * NODES + nl;
    float4 acc = make_float4(0.f, 0.f, 0.f, 0.f);
    float4 acc2 = make_float4(0.f, 0.f, 0.f, 0.f);
    if (node < n) {
        const float di = dinv[node];
        const float c = di * di;
        const float4 sv = *reinterpret_cast<const float4*>(&X[(long long)node * K + j]);
        acc.x = sv.x * c; acc.y = sv.y * c; acc.z = sv.z * c; acc.w = sv.w * c;
        int e = rp[node];
        const int end = rp[node + 1];
        for (; e + 2 <= end; e += 2) {
            const int2 c0 = cw[e];
            const int2 c1 = cw[e + 1];
            const float4 h0 = *reinterpret_cast<const float4*>(&X[(long long)c0.x * K + j]);
            const float4 h1 = *reinterpret_cast<const float4*>(&X[(long long)c1.x * K + j]);
            const float w0 = __int_as_float(c0.y);
            const float w1 = __int_as_float(c1.y);
            acc.x += h0.x * w0; acc.y += h0.y * w0; acc.z += h0.z * w0; acc.w += h0.w * w0;
            acc2.x += h1.x * w1; acc2.y += h1.y * w1; acc2.z += h1.z * w1; acc2.w += h1.w * w1;
        }
        if (e < end) {
            const int2 c0 = cw[e];
            const float4 h0 = *reinterpret_cast<const float4*>(&X[(long long)c0.x * K + j]);
            const float w0 = __int_as_float(c0.y);
            acc.x += h0.x * w0; acc.y += h0.y * w0; acc.z += h0.z * w0; acc.w += h0.w * w0;
        }
        acc.x += acc2.x; acc.y += acc2.y; acc.z += acc2.z; acc.w += acc2.w;
    }
    *reinterpret_cast<float4*>(&agg[nl * AS + j]) = acc;
    __syncthreads();

    // ---- phase B ----
    constexpr int CG = F / 4;
    static_assert(NODES * CG == 2 * 256, "tile mismatch");
    const int r0 = (threadIdx.x / CG) * 2;
    const int cg = (threadIdx.x % CG) * 4;
    float4 o0 = make_float4(0.f, 0.f, 0.f, 0.f);
    float4 o1 = make_float4(0.f, 0.f, 0.f, 0.f);
#pragma unroll 8
    for (int k = 0; k < K; ++k) {
        const float4 wv = *reinterpret_cast<const float4*>(&W[k * F + cg]);
        const float x0 = agg[r0 * AS + k];
        const float x1 = agg[(r0 + 1) * AS + k];
        o0.x += x0 * wv.x; o0.y += x0 * wv.y; o0.z += x0 * wv.z; o0.w += x0 * wv.w;
        o1.x += x1 * wv.x; o1.y += x1 * wv.y; o1.z += x1 * wv.z; o1.w += x1 * wv.w;
    }
    const float4 bv = *reinterpret_cast<const float4*>(&bias[cg]);
    o0.x += bv.x; o0.y += bv.y; o0.z += bv.z; o0.w += bv.w;
    o1.x += bv.x; o1.y += bv.y; o1.z += bv.z; o1.w += bv.w;
    if (RELU_OUT) {
        o0.x = fmaxf(o0.x, 0.f); o0.y = fmaxf(o0.y, 0.f);
        o0.z = fmaxf(o0.z, 0.f); o0.w = fmaxf(o0.w, 0.f);
        o1.x = fmaxf(o1.x, 0.f); o1.y = fmaxf(o1.y, 0.f);
        o1.z = fmaxf(o1.z, 0.f); o1.w = fmaxf(o1.w, 0.f);
    }
    const int row0 = blockIdx.x * NODES + r0;
    if (row0 < n)
        *reinterpret_cast<float4*>(&out[(long long)row0 * F + cg]) = o0;
    if (row0 + 1 < n)
        *reinterpret_cast<float4*>(&out[(long long)(row0 + 1) * F + cg]) = o1;
}

// ---------------- fused layer-3 gather + pool partials ----------------
// Spart[g*PARTS+part][128] = sum over assigned nodes of (Ahat h2)[node]
__device__ __forceinline__ int lower_bound_i(const int* __restrict__ a, int n, int key) {
    int lo = 0, hi = n;
    while (lo < hi) {
        int mid = (lo + hi) >> 1;
        if (a[mid] < key) lo = mid + 1; else hi = mid;
    }
    return lo;
}

__global__ __launch_bounds__(256) void gather_pool(const float* __restrict__ H,
                                                   const int* __restrict__ rp,
                                                   const int2* __restrict__ cw,
                                                   const float* __restrict__ dinv,
                                                   const int* __restrict__ batch,
                                                   float* __restrict__ Spart, int n) {
    __shared__ float red[8 * 128];
    const int g = blockIdx.x / PARTS;
    const int part = blockIdx.x % PARTS;
    const int slot = threadIdx.x >> 5;       // 0..7
    const int f4 = (threadIdx.x & 31) * 4;   // 0,4,...,124
    const int start = lower_bound_i(batch, n, g);
    const int end = lower_bound_i(batch, n, g + 1);
    float4 acc = make_float4(0.f, 0.f, 0.f, 0.f);
    for (int node = start + part * 8 + slot; node < end; node += PARTS * 8) {
        const float di = dinv[node];
        const float c = di * di;
        const float4 sv = *reinterpret_cast<const float4*>(&H[(long long)node * 128 + f4]);
        acc.x += sv.x * c; acc.y += sv.y * c; acc.z += sv.z * c; acc.w += sv.w * c;
        int e = rp[node];
        const int eend = rp[node + 1];
        float4 acc2 = make_float4(0.f, 0.f, 0.f, 0.f);
        for (; e + 2 <= eend; e += 2) {
            const int2 c0 = cw[e];
            const int2 c1 = cw[e + 1];
            const float4 h0 = *reinterpret_cast<const float4*>(&H[(long long)c0.x * 128 + f4]);
            const float4 h1 = *reinterpret_cast<const float4*>(&H[(long long)c1.x * 128 + f4]);
            const float w0 = __int_as_float(c0.y);
            const float w1 = __int_as_float(c1.y);
            acc.x += h0.x * w0; acc.y += h0.y * w0; acc.z += h0.z * w0; acc.w += h0.w * w0;
            acc2.x += h1.x * w1; acc2.y += h1.y * w1; acc2.z += h1.z * w1; acc2.w += h1.w * w1;
        }
        if (e < eend) {
            const int2 c0 = cw[e];
            const float4 h0 = *reinterpret_cast<const float4*>(&H[(long long)c0.x * 128 + f4]);
            const float w0 = __int_as_float(c0.y);
            acc.x += h0.x * w0; acc.y += h0.y * w0; acc.z += h0.z * w0; acc.w += h0.w * w0;
        }
        acc.x += acc2.x; acc.y += acc2.y; acc.z += acc2.z; acc.w += acc2.w;
    }
    *reinterpret_cast<float4*>(&red[slot * 128 + f4]) = acc;
    __syncthreads();
    const int t = threadIdx.x;
    if (t < 128) {
        float s = 0.f;
#pragma unroll
        for (int sl = 0; sl < 8; ++sl) s += red[sl * 128 + t];
        Spart[(long long)blockIdx.x * 128 + t] = s;
    }
}

// ---------------- final: out[g] = ((S@W3)*inv + b3*bscale) @ Wlin + blin -----
__global__ __launch_bounds__(256) void final_k(const float* __restrict__ Spart,
                                               const int* __restrict__ batch,
                                               const float* __restrict__ W3,
                                               const float* __restrict__ b3,
                                               const float* __restrict__ Wlin,
                                               const float* __restrict__ blin,
                                               float* __restrict__ out, int n) {
    __shared__ float srow[128];
    __shared__ float prow[256];
    const int g = blockIdx.x;
    const int t = threadIdx.x;
    if (t < 128) {
        float s = 0.f;
#pragma unroll
        for (int p = 0; p < PARTS; ++p)
            s += Spart[(long long)(g * PARTS + p) * 128 + t];
        srow[t] = s;
    }
    __syncthreads();
    const int start = lower_bound_i(batch, n, g);
    const int end = lower_bound_i(batch, n, g + 1);
    const float cnt = (float)(end - start);
    const float inv = 1.0f / fmaxf(cnt, 1.0f);
    const float bscale = cnt * inv;   // 0 for empty graph, else 1
    float p = 0.f;
    for (int k = 0; k < 128; ++k) p += srow[k] * W3[k * 256 + t];
    prow[t] = p * inv + b3[t] * bscale;
    __syncthreads();
    if (t < 10) {
        float a = blin[t];
        for (int f = 0; f < 256; ++f) a += prow[f] * Wlin[f * 10 + t];
        out[g * 10 + t] = a;
    }
}

extern "C" void kernel_launch(void* const* d_in, const int* in_sizes, int n_in,
                              void* d_out, int out_size, void* d_ws, size_t ws_size,
                              hipStream_t stream) {
    const float* x     = (const float*)d_in[0];
    const int*   ei    = (const int*)d_in[1];   // [2,E]: row0=src, row1=dst
    const int*   batch = (const int*)d_in[2];
    const float* W1    = (const float*)d_in[3];
    const float* bc1   = (const float*)d_in[4];
    const float* W2    = (const float*)d_in[5];
    const float* bc2   = (const float*)d_in[6];
    const float* W3    = (const float*)d_in[7];
    const float* bc3   = (const float*)d_in[8];
    const float* Wlin  = (const float*)d_in[9];
    const float* blin  = (const float*)d_in[10];
    float* out = (float*)d_out;

    char* w = (char*)d_ws;
    int*   deg    = (int*)w;               w += 131072 * 4;
    int*   rp     = (int*)w;               w += 131072 * 4;   // row_ptr[N+1]
    int*   cursor = (int*)w;               w += 131072 * 4;
    int*   bsum   = (int*)w;               w += 256 * 4;
    float* dinv   = (float*)w;             w += 131072 * 4;
    int2*  cw     = (int2*)w;              w += (long long)NE * 8;
    float* P      = (float*)w;             w += (long long)NN * 128 * 4;  // h2
    float* Q      = (float*)w;             w += (long long)NN * 128 * 4;  // h1
    float* Spart  = (float*)w;             w += (long long)NG * PARTS * 128 * 4;

    const int nbScanA = (NN + 1023) / 1024;  // 98 <= 128

    // -------- degree + dinv + CSR --------
    hipMemsetAsync(deg, 0, NN * sizeof(int), stream);
    deg_count<<<(NE + 255) / 256, 256, 0, stream>>>(ei + NE, deg, NE);
    scanA<<<nbScanA, 256, 0, stream>>>(deg, rp, bsum, NN);
    scanB<<<1, 128, 0, stream>>>(bsum, nbScanA);
    scanC<<<(NN + 256) / 256, 256, 0, stream>>>(rp, bsum, cursor, deg, dinv, NN, NE);
    fill_csr<<<(NE + 255) / 256, 256, 0, stream>>>(ei, dinv, cursor, cw, NE);

    // -------- layer 1 fused: h1 = relu((Ahat x)@W1 + b1) --------
    gather_gemm<32, 64, 32, true><<<(NN + 31) / 32, 256, 0, stream>>>(
        x, rp, cw, dinv, W1, bc1, Q, NN);

    // -------- layer 2 fused: h2 = relu((Ahat h1)@W2 + b2) --------
    gather_gemm<64, 128, 16, true><<<(NN + 15) / 16, 256, 0, stream>>>(
        Q, rp, cw, dinv, W2, bc2, P, NN);

    // -------- layer 3 + pool fused: Spart = partial segment sums of Ahat h2 ----
    gather_pool<<<NG * PARTS, 256, 0, stream>>>(P, rp, cw, dinv, batch, Spart, NN);

    // -------- final --------
    final_k<<<NG, 256, 0, stream>>>(Spart, batch, W3, bc3, Wlin, blin, out, NN);
}

// Round 5
// 262.114 us; speedup vs baseline: 22.0230x; 1.0949x over previous
//
#include <hip/hip_runtime.h>
#include <hip/hip_bf16.h>

// GCN restructured + fused:
//   h1 = relu((Ahat x) @ W1 + b1)   -- fused gather+GEMM, K=32 -> F=64
//   h2 = relu((Ahat h1) @ W2 + b2)  -- fused gather+GEMM, K=64 -> F=128
//   Spart = per-graph partial segment sums of (Ahat h2)   -- fused gather+pool
//   out = ((sum(Spart)@W3)/cnt + b3) @ Wlin + blin
// CSR built per call. No atomics in hot path.
// R5: W staged global->reg (pre-gather, overlapped) ->LDS; 4-deep gather unroll.

#define NN 100000
#define NE 800000
#define NG 512
#define PARTS 4

// ---------------- degree ----------------
__global__ __launch_bounds__(256) void deg_count(const int* __restrict__ dst,
                                                 int* __restrict__ deg, int nE) {
    int e = blockIdx.x * 256 + threadIdx.x;
    if (e < nE) atomicAdd(&deg[dst[e]], 1);
}

// ---------------- exclusive scan of deg -> row_ptr ----------------
__global__ __launch_bounds__(256) void scanA(const int* __restrict__ deg,
                                             int* __restrict__ ex,
                                             int* __restrict__ bsum, int n) {
    __shared__ int sdata[256];
    const int t = threadIdx.x;
    const int base = blockIdx.x * 1024;
    const int idx = base + t * 4;
    int v[4];
#pragma unroll
    for (int k = 0; k < 4; ++k) v[k] = (idx + k < n) ? deg[idx + k] : 0;
    int ts = v[0] + v[1] + v[2] + v[3];
    sdata[t] = ts;
    __syncthreads();
    for (int off = 1; off < 256; off <<= 1) {
        int val = (t >= off) ? sdata[t - off] : 0;
        __syncthreads();
        sdata[t] += val;
        __syncthreads();
    }
    int run = sdata[t] - ts;
    if (t == 255) bsum[blockIdx.x] = sdata[255];
#pragma unroll
    for (int k = 0; k < 4; ++k) {
        if (idx + k < n) ex[idx + k] = run;
        run += v[k];
    }
}

__global__ __launch_bounds__(128) void scanB(int* __restrict__ bsum, int nb) {
    __shared__ int s[128];
    const int t = threadIdx.x;
    int orig = (t < nb) ? bsum[t] : 0;
    s[t] = orig;
    __syncthreads();
    for (int off = 1; off < 128; off <<= 1) {
        int val = (t >= off) ? s[t - off] : 0;
        __syncthreads();
        s[t] += val;
        __syncthreads();
    }
    if (t < nb) bsum[t] = s[t] - orig;
}

__global__ __launch_bounds__(256) void scanC(int* __restrict__ rp,
                                             const int* __restrict__ bsum,
                                             int* __restrict__ cursor,
                                             const int* __restrict__ deg,
                                             float* __restrict__ dinv,
                                             int n, int total) {
    int i = blockIdx.x * 256 + threadIdx.x;
    if (i < n) {
        int v = rp[i] + bsum[i >> 10];
        rp[i] = v;
        cursor[i] = v;
        dinv[i] = rsqrtf((float)deg[i] + 1.0f);
    }
    if (i == n) rp[n] = total;
}

// ---------------- CSR fill ----------------
__global__ __launch_bounds__(256) void fill_csr(const int* __restrict__ ei,
                                                const float* __restrict__ dinv,
                                                int* __restrict__ cursor,
                                                int2* __restrict__ cw, int nE) {
    int e = blockIdx.x * 256 + threadIdx.x;
    if (e >= nE) return;
    const int s = ei[e];
    const int d = ei[nE + e];
    const int pos = atomicAdd(&cursor[d], 1);
    const float wv = dinv[s] * dinv[d];
    cw[pos] = make_int2(s, __float_as_int(wv));
}

#define FMA4(A, H, W_) do { (A).x += (H).x * (W_); (A).y += (H).y * (W_); \
                            (A).z += (H).z * (W_); (A).w += (H).w * (W_); } while (0)

// ---------------- fused: out = relu?((Ahat X) @ W + b) ----------------
// W: global->registers (issued before gather, overlaps) -> LDS after gather.
// Phase A: 4-deep unrolled CSR gather into LDS. Phase B: 2 rows x 4 cols/thread.
template <int K, int F, int NODES, bool RELU_OUT>
__global__ __launch_bounds__(256) void gather_gemm(const float* __restrict__ X,
                                                   const int* __restrict__ rp,
                                                   const int2* __restrict__ cw,
                                                   const float* __restrict__ dinv,
                                                   const float* __restrict__ W,
                                                   const float* __restrict__ bias,
                                                   float* __restrict__ out, int n) {
    constexpr int TPN = K / 4;
    static_assert(256 / TPN == NODES, "node count mismatch");
    constexpr int AS = K + 4;
    constexpr int WPT = K * F / 4 / 256;   // float4 of W per thread
    __shared__ float agg[NODES * AS];
    __shared__ float Wl[K * F];

    // issue W loads early; they complete while the gather runs
    float4 wr[WPT];
#pragma unroll
    for (int i = 0; i < WPT; ++i)
        wr[i] = *reinterpret_cast<const float4*>(&W[(threadIdx.x + i * 256) * 4]);

    // ---- phase A: gather-aggregate into LDS ----
    const int nl = threadIdx.x / TPN;
    const int j = (threadIdx.x % TPN) * 4;
    const int node = blockIdx.x * NODES + nl;
    float4 a0 = make_float4(0.f, 0.f, 0.f, 0.f);
    float4 a1 = a0, a2 = a0, a3 = a0;
    if (node < n) {
        const float di = dinv[node];
        const float c = di * di;
        const float4 sv = *reinterpret_cast<const float4*>(&X[(long long)node * K + j]);
        FMA4(a0, sv, c);
        int e = rp[node];
        const int end = rp[node + 1];
        for (; e + 4 <= end; e += 4) {
            const int2 c0 = cw[e];
            const int2 c1 = cw[e + 1];
            const int2 c2 = cw[e + 2];
            const int2 c3 = cw[e + 3];
            const float4 h0 = *reinterpret_cast<const float4*>(&X[(long long)c0.x * K + j]);
            const float4 h1 = *reinterpret_cast<const float4*>(&X[(long long)c1.x * K + j]);
            const float4 h2v = *reinterpret_cast<const float4*>(&X[(long long)c2.x * K + j]);
            const float4 h3 = *reinterpret_cast<const float4*>(&X[(long long)c3.x * K + j]);
            FMA4(a0, h0, __int_as_float(c0.y));
            FMA4(a1, h1, __int_as_float(c1.y));
            FMA4(a2, h2v, __int_as_float(c2.y));
            FMA4(a3, h3, __int_as_float(c3.y));
        }
        if (e + 2 <= end) {
            const int2 c0 = cw[e];
            const int2 c1 = cw[e + 1];
            const float4 h0 = *reinterpret_cast<const float4*>(&X[(long long)c0.x * K + j]);
            const float4 h1 = *reinterpret_cast<const float4*>(&X[(long long)c1.x * K + j]);
            FMA4(a0, h0, __int_as_float(c0.y));
            FMA4(a1, h1, __int_as_float(c1.y));
            e += 2;
        }
        if (e < end) {
            const int2 c0 = cw[e];
            const float4 h0 = *reinterpret_cast<const float4*>(&X[(long long)c0.x * K + j]);
            FMA4(a0, h0, __int_as_float(c0.y));
        }
        a0.x += a1.x + a2.x + a3.x; a0.y += a1.y + a2.y + a3.y;
        a0.z += a1.z + a2.z + a3.z; a0.w += a1.w + a2.w + a3.w;
    }
    *reinterpret_cast<float4*>(&agg[nl * AS + j]) = a0;

    // write W registers to LDS, then one barrier covers both
#pragma unroll
    for (int i = 0; i < WPT; ++i)
        *reinterpret_cast<float4*>(&Wl[(threadIdx.x + i * 256) * 4]) = wr[i];
    __syncthreads();

    // ---- phase B: [NODES x K] @ [K x F], 2 rows x 4 cols per thread ----
    constexpr int CG = F / 4;
    static_assert(NODES * CG == 2 * 256, "tile mismatch");
    const int r0 = (threadIdx.x / CG) * 2;
    const int cg = (threadIdx.x % CG) * 4;
    float4 o0 = make_float4(0.f, 0.f, 0.f, 0.f);
    float4 o1 = o0;
#pragma unroll 8
    for (int k = 0; k < K; ++k) {
        const float4 wv = *reinterpret_cast<const float4*>(&Wl[k * F + cg]);
        const float x0 = agg[r0 * AS + k];
        const float x1 = agg[(r0 + 1) * AS + k];
        FMA4(o0, wv, x0);
        FMA4(o1, wv, x1);
    }
    const float4 bv = *reinterpret_cast<const float4*>(&bias[cg]);
    o0.x += bv.x; o0.y += bv.y; o0.z += bv.z; o0.w += bv.w;
    o1.x += bv.x; o1.y += bv.y; o1.z += bv.z; o1.w += bv.w;
    if (RELU_OUT) {
        o0.x = fmaxf(o0.x, 0.f); o0.y = fmaxf(o0.y, 0.f);
        o0.z = fmaxf(o0.z, 0.f); o0.w = fmaxf(o0.w, 0.f);
        o1.x = fmaxf(o1.x, 0.f); o1.y = fmaxf(o1.y, 0.f);
        o1.z = fmaxf(o1.z, 0.f); o1.w = fmaxf(o1.w, 0.f);
    }
    const int row0 = blockIdx.x * NODES + r0;
    if (row0 < n)
        *reinterpret_cast<float4*>(&out[(long long)row0 * F + cg]) = o0;
    if (row0 + 1 < n)
        *reinterpret_cast<float4*>(&out[(long long)(row0 + 1) * F + cg]) = o1;
}

// ---------------- fused layer-3 gather + pool partials ----------------
__device__ __forceinline__ int lower_bound_i(const int* __restrict__ a, int n, int key) {
    int lo = 0, hi = n;
    while (lo < hi) {
        int mid = (lo + hi) >> 1;
        if (a[mid] < key) lo = mid + 1; else hi = mid;
    }
    return lo;
}

__global__ __launch_bounds__(256) void gather_pool(const float* __restrict__ H,
                                                   const int* __restrict__ rp,
                                                   const int2* __restrict__ cw,
                                                   const float* __restrict__ dinv,
                                                   const int* __restrict__ batch,
                                                   float* __restrict__ Spart, int n) {
    __shared__ float red[8 * 128];
    const int g = blockIdx.x / PARTS;
    const int part = blockIdx.x % PARTS;
    const int slot = threadIdx.x >> 5;
    const int f4 = (threadIdx.x & 31) * 4;
    const int start = lower_bound_i(batch, n, g);
    const int end = lower_bound_i(batch, n, g + 1);
    float4 acc = make_float4(0.f, 0.f, 0.f, 0.f);
    for (int node = start + part * 8 + slot; node < end; node += PARTS * 8) {
        const float di = dinv[node];
        const float c = di * di;
        const float4 sv = *reinterpret_cast<const float4*>(&H[(long long)node * 128 + f4]);
        FMA4(acc, sv, c);
        float4 a1 = make_float4(0.f, 0.f, 0.f, 0.f);
        float4 a2 = a1, a3 = a1;
        int e = rp[node];
        const int eend = rp[node + 1];
        for (; e + 4 <= eend; e += 4) {
            const int2 c0 = cw[e];
            const int2 c1 = cw[e + 1];
            const int2 c2 = cw[e + 2];
            const int2 c3 = cw[e + 3];
            const float4 h0 = *reinterpret_cast<const float4*>(&H[(long long)c0.x * 128 + f4]);
            const float4 h1 = *reinterpret_cast<const float4*>(&H[(long long)c1.x * 128 + f4]);
            const float4 h2v = *reinterpret_cast<const float4*>(&H[(long long)c2.x * 128 + f4]);
            const float4 h3 = *reinterpret_cast<const float4*>(&H[(long long)c3.x * 128 + f4]);
            FMA4(acc, h0, __int_as_float(c0.y));
            FMA4(a1, h1, __int_as_float(c1.y));
            FMA4(a2, h2v, __int_as_float(c2.y));
            FMA4(a3, h3, __int_as_float(c3.y));
        }
        if (e + 2 <= eend) {
            const int2 c0 = cw[e];
            const int2 c1 = cw[e + 1];
            const float4 h0 = *reinterpret_cast<const float4*>(&H[(long long)c0.x * 128 + f4]);
            const float4 h1 = *reinterpret_cast<const float4*>(&H[(long long)c1.x * 128 + f4]);
            FMA4(acc, h0, __int_as_float(c0.y));
            FMA4(a1, h1, __int_as_float(c1.y));
            e += 2;
        }
        if (e < eend) {
            const int2 c0 = cw[e];
            const float4 h0 = *reinterpret_cast<const float4*>(&H[(long long)c0.x * 128 + f4]);
            FMA4(acc, h0, __int_as_float(c0.y));
        }
        acc.x += a1.x + a2.x + a3.x; acc.y += a1.y + a2.y + a3.y;
        acc.z += a1.z + a2.z + a3.z; acc.w += a1.w + a2.w + a3.w;
    }
    *reinterpret_cast<float4*>(&red[slot * 128 + f4]) = acc;
    __syncthreads();
    const int t = threadIdx.x;
    if (t < 128) {
        float s = 0.f;
#pragma unroll
        for (int sl = 0; sl < 8; ++sl) s += red[sl * 128 + t];
        Spart[(long long)blockIdx.x * 128 + t] = s;
    }
}

// ---------------- final ----------------
__global__ __launch_bounds__(256) void final_k(const float* __restrict__ Spart,
                                               const int* __restrict__ batch,
                                               const float* __restrict__ W3,
                                               const float* __restrict__ b3,
                                               const float* __restrict__ Wlin,
                                               const float* __restrict__ blin,
                                               float* __restrict__ out, int n) {
    __shared__ float srow[128];
    __shared__ float prow[256];
    const int g = blockIdx.x;
    const int t = threadIdx.x;
    if (t < 128) {
        float s = 0.f;
#pragma unroll
        for (int p = 0; p < PARTS; ++p)
            s += Spart[(long long)(g * PARTS + p) * 128 + t];
        srow[t] = s;
    }
    __syncthreads();
    const int start = lower_bound_i(batch, n, g);
    const int end = lower_bound_i(batch, n, g + 1);
    const float cnt = (float)(end - start);
    const float inv = 1.0f / fmaxf(cnt, 1.0f);
    const float bscale = cnt * inv;
    float p = 0.f;
    for (int k = 0; k < 128; ++k) p += srow[k] * W3[k * 256 + t];
    prow[t] = p * inv + b3[t] * bscale;
    __syncthreads();
    if (t < 10) {
        float a = blin[t];
        for (int f = 0; f < 256; ++f) a += prow[f] * Wlin[f * 10 + t];
        out[g * 10 + t] = a;
    }
}

extern "C" void kernel_launch(void* const* d_in, const int* in_sizes, int n_in,
                              void* d_out, int out_size, void* d_ws, size_t ws_size,
                              hipStream_t stream) {
    const float* x     = (const float*)d_in[0];
    const int*   ei    = (const int*)d_in[1];
    const int*   batch = (const int*)d_in[2];
    const float* W1    = (const float*)d_in[3];
    const float* bc1   = (const float*)d_in[4];
    const float* W2    = (const float*)d_in[5];
    const float* bc2   = (const float*)d_in[6];
    const float* W3    = (const float*)d_in[7];
    const float* bc3   = (const float*)d_in[8];
    const float* Wlin  = (const float*)d_in[9];
    const float* blin  = (const float*)d_in[10];
    float* out = (float*)d_out;

    char* w = (char*)d_ws;
    int*   deg    = (int*)w;               w += 131072 * 4;
    int*   rp     = (int*)w;               w += 131072 * 4;
    int*   cursor = (int*)w;               w += 131072 * 4;
    int*   bsum   = (int*)w;               w += 256 * 4;
    float* dinv   = (float*)w;             w += 131072 * 4;
    int2*  cw     = (int2*)w;              w += (long long)NE * 8;
    float* P      = (float*)w;             w += (long long)NN * 128 * 4;  // h2
    float* Q      = (float*)w;             w += (long long)NN * 128 * 4;  // h1
    float* Spart  = (float*)w;             w += (long long)NG * PARTS * 128 * 4;

    const int nbScanA = (NN + 1023) / 1024;

    hipMemsetAsync(deg, 0, NN * sizeof(int), stream);
    deg_count<<<(NE + 255) / 256, 256, 0, stream>>>(ei + NE, deg, NE);
    scanA<<<nbScanA, 256, 0, stream>>>(deg, rp, bsum, NN);
    scanB<<<1, 128, 0, stream>>>(bsum, nbScanA);
    scanC<<<(NN + 256) / 256, 256, 0, stream>>>(rp, bsum, cursor, deg, dinv, NN, NE);
    fill_csr<<<(NE + 255) / 256, 256, 0, stream>>>(ei, dinv, cursor, cw, NE);

    gather_gemm<32, 64, 32, true><<<(NN + 31) / 32, 256, 0, stream>>>(
        x, rp, cw, dinv, W1, bc1, Q, NN);

    gather_gemm<64, 128, 16, true><<<(NN + 15) / 16, 256, 0, stream>>>(
        Q, rp, cw, dinv, W2, bc2, P, NN);

    gather_pool<<<NG * PARTS, 256, 0, stream>>>(P, rp, cw, dinv, batch, Spart, NN);

    final_k<<<NG, 256, 0, stream>>>(Spart, batch, W3, bc3, Wlin, blin, out, NN);
}

// Round 6
// 223.062 us; speedup vs baseline: 25.8786x; 1.1751x over previous
//
#include <hip/hip_runtime.h>
#include <hip/hip_bf16.h>

// GCN restructured + fused, bf16 intermediates:
//   h1 = relu((Ahat x) @ W1 + b1)   -- fused gather+GEMM, K=32 fp32 -> F=64 bf16
//   h2 = relu((Ahat h1) @ W2 + b2)  -- fused gather(bf16)+GEMM, K=64 -> F=128 bf16
//   Spart = per-graph partial segment sums of (Ahat h2)  -- fused gather(bf16)+pool
//   out = ((sum(Spart)@W3)/cnt + b3) @ Wlin + blin
// All accumulation in fp32; bf16 only for the stored/gathered h rows.

#define NN 100000
#define NE 800000
#define NG 512
#define PARTS 4

typedef unsigned int u32;

// RNE pack of two fp32 -> packed bf16x2 (lo in low half)
__device__ __forceinline__ u32 pack_bf2(float lo, float hi) {
    u32 ul = __float_as_uint(lo);
    u32 uh = __float_as_uint(hi);
    ul = (ul + 0x7fffu + ((ul >> 16) & 1u)) >> 16;
    uh = (uh + 0x7fffu + ((uh >> 16) & 1u)) & 0xffff0000u;
    return uh | ul;
}

// acc[0..7] += unpack8(v) * w
#define BF_FMA8(ACC, V, W_) do { \
    (ACC)[0] += __uint_as_float((V).x << 16) * (W_); \
    (ACC)[1] += __uint_as_float((V).x & 0xffff0000u) * (W_); \
    (ACC)[2] += __uint_as_float((V).y << 16) * (W_); \
    (ACC)[3] += __uint_as_float((V).y & 0xffff0000u) * (W_); \
    (ACC)[4] += __uint_as_float((V).z << 16) * (W_); \
    (ACC)[5] += __uint_as_float((V).z & 0xffff0000u) * (W_); \
    (ACC)[6] += __uint_as_float((V).w << 16) * (W_); \
    (ACC)[7] += __uint_as_float((V).w & 0xffff0000u) * (W_); \
} while (0)

#define FMA4(A, H, W_) do { (A).x += (H).x * (W_); (A).y += (H).y * (W_); \
                            (A).z += (H).z * (W_); (A).w += (H).w * (W_); } while (0)

// ---------------- degree ----------------
__global__ __launch_bounds__(256) void deg_count(const int* __restrict__ dst,
                                                 int* __restrict__ deg, int nE) {
    int e = blockIdx.x * 256 + threadIdx.x;
    if (e < nE) atomicAdd(&deg[dst[e]], 1);
}

// ---------------- exclusive scan of deg -> row_ptr ----------------
__global__ __launch_bounds__(256) void scanA(const int* __restrict__ deg,
                                             int* __restrict__ ex,
                                             int* __restrict__ bsum, int n) {
    __shared__ int sdata[256];
    const int t = threadIdx.x;
    const int base = blockIdx.x * 1024;
    const int idx = base + t * 4;
    int v[4];
#pragma unroll
    for (int k = 0; k < 4; ++k) v[k] = (idx + k < n) ? deg[idx + k] : 0;
    int ts = v[0] + v[1] + v[2] + v[3];
    sdata[t] = ts;
    __syncthreads();
    for (int off = 1; off < 256; off <<= 1) {
        int val = (t >= off) ? sdata[t - off] : 0;
        __syncthreads();
        sdata[t] += val;
        __syncthreads();
    }
    int run = sdata[t] - ts;
    if (t == 255) bsum[blockIdx.x] = sdata[255];
#pragma unroll
    for (int k = 0; k < 4; ++k) {
        if (idx + k < n) ex[idx + k] = run;
        run += v[k];
    }
}

__global__ __launch_bounds__(128) void scanB(int* __restrict__ bsum, int nb) {
    __shared__ int s[128];
    const int t = threadIdx.x;
    int orig = (t < nb) ? bsum[t] : 0;
    s[t] = orig;
    __syncthreads();
    for (int off = 1; off < 128; off <<= 1) {
        int val = (t >= off) ? s[t - off] : 0;
        __syncthreads();
        s[t] += val;
        __syncthreads();
    }
    if (t < nb) bsum[t] = s[t] - orig;
}

__global__ __launch_bounds__(256) void scanC(int* __restrict__ rp,
                                             const int* __restrict__ bsum,
                                             int* __restrict__ cursor,
                                             const int* __restrict__ deg,
                                             float* __restrict__ dinv,
                                             int n, int total) {
    int i = blockIdx.x * 256 + threadIdx.x;
    if (i < n) {
        int v = rp[i] + bsum[i >> 10];
        rp[i] = v;
        cursor[i] = v;
        dinv[i] = rsqrtf((float)deg[i] + 1.0f);
    }
    if (i == n) rp[n] = total;
}

// ---------------- CSR fill ----------------
__global__ __launch_bounds__(256) void fill_csr(const int* __restrict__ ei,
                                                const float* __restrict__ dinv,
                                                int* __restrict__ cursor,
                                                int2* __restrict__ cw, int nE) {
    int e = blockIdx.x * 256 + threadIdx.x;
    if (e >= nE) return;
    const int s = ei[e];
    const int d = ei[nE + e];
    const int pos = atomicAdd(&cursor[d], 1);
    const float wv = dinv[s] * dinv[d];
    cw[pos] = make_int2(s, __float_as_int(wv));
}

// ---------------- layer 1: h1 = relu((Ahat x)@W1 + b1), fp32 in, bf16 out ----
// 32 nodes/block; phase A: 8 threads/node (float4); phase B: 2 rows x 4 cols.
__global__ __launch_bounds__(256) void gather_gemm_l1(const float* __restrict__ X,
                                                      const int* __restrict__ rp,
                                                      const int2* __restrict__ cw,
                                                      const float* __restrict__ dinv,
                                                      const float* __restrict__ W,
                                                      const float* __restrict__ bias,
                                                      u32* __restrict__ out, int n) {
    constexpr int AS = 36;
    __shared__ float agg[32 * AS];
    __shared__ float Wl[32 * 64];
    float4 wr[2];
#pragma unroll
    for (int i = 0; i < 2; ++i)
        wr[i] = *reinterpret_cast<const float4*>(&W[(threadIdx.x + i * 256) * 4]);

    const int nl = threadIdx.x >> 3;
    const int j = (threadIdx.x & 7) * 4;
    const int node = blockIdx.x * 32 + nl;
    float4 a0 = make_float4(0.f, 0.f, 0.f, 0.f);
    float4 a1 = a0, a2 = a0, a3 = a0;
    if (node < n) {
        const float di = dinv[node];
        const float c = di * di;
        const float4 sv = *reinterpret_cast<const float4*>(&X[(long long)node * 32 + j]);
        FMA4(a0, sv, c);
        int e = rp[node];
        const int end = rp[node + 1];
        for (; e + 4 <= end; e += 4) {
            const int2 c0 = cw[e], c1 = cw[e + 1], c2 = cw[e + 2], c3 = cw[e + 3];
            const float4 h0 = *reinterpret_cast<const float4*>(&X[(long long)c0.x * 32 + j]);
            const float4 h1 = *reinterpret_cast<const float4*>(&X[(long long)c1.x * 32 + j]);
            const float4 h2 = *reinterpret_cast<const float4*>(&X[(long long)c2.x * 32 + j]);
            const float4 h3 = *reinterpret_cast<const float4*>(&X[(long long)c3.x * 32 + j]);
            FMA4(a0, h0, __int_as_float(c0.y));
            FMA4(a1, h1, __int_as_float(c1.y));
            FMA4(a2, h2, __int_as_float(c2.y));
            FMA4(a3, h3, __int_as_float(c3.y));
        }
        if (e + 2 <= end) {
            const int2 c0 = cw[e], c1 = cw[e + 1];
            const float4 h0 = *reinterpret_cast<const float4*>(&X[(long long)c0.x * 32 + j]);
            const float4 h1 = *reinterpret_cast<const float4*>(&X[(long long)c1.x * 32 + j]);
            FMA4(a0, h0, __int_as_float(c0.y));
            FMA4(a1, h1, __int_as_float(c1.y));
            e += 2;
        }
        if (e < end) {
            const int2 c0 = cw[e];
            const float4 h0 = *reinterpret_cast<const float4*>(&X[(long long)c0.x * 32 + j]);
            FMA4(a0, h0, __int_as_float(c0.y));
        }
        a0.x += a1.x + a2.x + a3.x; a0.y += a1.y + a2.y + a3.y;
        a0.z += a1.z + a2.z + a3.z; a0.w += a1.w + a2.w + a3.w;
    }
    *reinterpret_cast<float4*>(&agg[nl * AS + j]) = a0;
#pragma unroll
    for (int i = 0; i < 2; ++i)
        *reinterpret_cast<float4*>(&Wl[(threadIdx.x + i * 256) * 4]) = wr[i];
    __syncthreads();

    // phase B: K=32, F=64
    const int r0 = (threadIdx.x >> 4) * 2;
    const int cg = (threadIdx.x & 15) * 4;
    float4 o0 = make_float4(0.f, 0.f, 0.f, 0.f);
    float4 o1 = o0;
#pragma unroll 8
    for (int k = 0; k < 32; ++k) {
        const float4 wv = *reinterpret_cast<const float4*>(&Wl[k * 64 + cg]);
        const float x0 = agg[r0 * AS + k];
        const float x1 = agg[(r0 + 1) * AS + k];
        FMA4(o0, wv, x0);
        FMA4(o1, wv, x1);
    }
    const float4 bv = *reinterpret_cast<const float4*>(&bias[cg]);
    o0.x = fmaxf(o0.x + bv.x, 0.f); o0.y = fmaxf(o0.y + bv.y, 0.f);
    o0.z = fmaxf(o0.z + bv.z, 0.f); o0.w = fmaxf(o0.w + bv.w, 0.f);
    o1.x = fmaxf(o1.x + bv.x, 0.f); o1.y = fmaxf(o1.y + bv.y, 0.f);
    o1.z = fmaxf(o1.z + bv.z, 0.f); o1.w = fmaxf(o1.w + bv.w, 0.f);
    const int row0 = blockIdx.x * 32 + r0;
    if (row0 < n)
        *reinterpret_cast<uint2*>(&out[(long long)row0 * 32 + (cg >> 1)]) =
            make_uint2(pack_bf2(o0.x, o0.y), pack_bf2(o0.z, o0.w));
    if (row0 + 1 < n)
        *reinterpret_cast<uint2*>(&out[(long long)(row0 + 1) * 32 + (cg >> 1)]) =
            make_uint2(pack_bf2(o1.x, o1.y), pack_bf2(o1.z, o1.w));
}

// ---------------- layer 2: h2 = relu((Ahat h1)@W2 + b2), bf16 in/out ----------
// 32 nodes/block; phase A: 8 threads/node (8 feats each, bf16x8 loads);
// phase B: 4 rows x 4 cols per thread, W2 (32 KB) staged reg->LDS.
__global__ __launch_bounds__(256) void gather_gemm_l2(const u32* __restrict__ X,
                                                      const int* __restrict__ rp,
                                                      const int2* __restrict__ cw,
                                                      const float* __restrict__ dinv,
                                                      const float* __restrict__ W,
                                                      const float* __restrict__ bias,
                                                      u32* __restrict__ out, int n) {
    constexpr int AS = 68;
    __shared__ float agg[32 * AS];
    __shared__ float Wl[64 * 128];
    float4 wr[8];
#pragma unroll
    for (int i = 0; i < 8; ++i)
        wr[i] = *reinterpret_cast<const float4*>(&W[(threadIdx.x + i * 256) * 4]);

    const int nl = threadIdx.x >> 3;
    const int j = threadIdx.x & 7;         // feature octet
    const int node = blockIdx.x * 32 + nl;
    float a0[8], a1[8], a2[8], a3[8];
#pragma unroll
    for (int q = 0; q < 8; ++q) { a0[q] = 0.f; a1[q] = 0.f; a2[q] = 0.f; a3[q] = 0.f; }
    if (node < n) {
        const float di = dinv[node];
        const float c = di * di;
        const uint4 sv = *reinterpret_cast<const uint4*>(&X[(long long)node * 32 + j * 4]);
        BF_FMA8(a0, sv, c);
        int e = rp[node];
        const int end = rp[node + 1];
        for (; e + 4 <= end; e += 4) {
            const int2 c0 = cw[e], c1 = cw[e + 1], c2 = cw[e + 2], c3 = cw[e + 3];
            const uint4 h0 = *reinterpret_cast<const uint4*>(&X[(long long)c0.x * 32 + j * 4]);
            const uint4 h1 = *reinterpret_cast<const uint4*>(&X[(long long)c1.x * 32 + j * 4]);
            const uint4 h2 = *reinterpret_cast<const uint4*>(&X[(long long)c2.x * 32 + j * 4]);
            const uint4 h3 = *reinterpret_cast<const uint4*>(&X[(long long)c3.x * 32 + j * 4]);
            BF_FMA8(a0, h0, __int_as_float(c0.y));
            BF_FMA8(a1, h1, __int_as_float(c1.y));
            BF_FMA8(a2, h2, __int_as_float(c2.y));
            BF_FMA8(a3, h3, __int_as_float(c3.y));
        }
        if (e + 2 <= end) {
            const int2 c0 = cw[e], c1 = cw[e + 1];
            const uint4 h0 = *reinterpret_cast<const uint4*>(&X[(long long)c0.x * 32 + j * 4]);
            const uint4 h1 = *reinterpret_cast<const uint4*>(&X[(long long)c1.x * 32 + j * 4]);
            BF_FMA8(a0, h0, __int_as_float(c0.y));
            BF_FMA8(a1, h1, __int_as_float(c1.y));
            e += 2;
        }
        if (e < end) {
            const int2 c0 = cw[e];
            const uint4 h0 = *reinterpret_cast<const uint4*>(&X[(long long)c0.x * 32 + j * 4]);
            BF_FMA8(a0, h0, __int_as_float(c0.y));
        }
#pragma unroll
        for (int q = 0; q < 8; ++q) a0[q] += a1[q] + a2[q] + a3[q];
    }
    *reinterpret_cast<float4*>(&agg[nl * AS + j * 8]) =
        make_float4(a0[0], a0[1], a0[2], a0[3]);
    *reinterpret_cast<float4*>(&agg[nl * AS + j * 8 + 4]) =
        make_float4(a0[4], a0[5], a0[6], a0[7]);
#pragma unroll
    for (int i = 0; i < 8; ++i)
        *reinterpret_cast<float4*>(&Wl[(threadIdx.x + i * 256) * 4]) = wr[i];
    __syncthreads();

    // phase B: K=64, F=128, 4 rows x 4 cols
    const int r0 = (threadIdx.x >> 5) * 4;
    const int cg = (threadIdx.x & 31) * 4;
    float4 o0 = make_float4(0.f, 0.f, 0.f, 0.f);
    float4 o1 = o0, o2 = o0, o3 = o0;
#pragma unroll 8
    for (int k = 0; k < 64; ++k) {
        const float4 wv = *reinterpret_cast<const float4*>(&Wl[k * 128 + cg]);
        const float x0 = agg[(r0 + 0) * AS + k];
        const float x1 = agg[(r0 + 1) * AS + k];
        const float x2 = agg[(r0 + 2) * AS + k];
        const float x3 = agg[(r0 + 3) * AS + k];
        FMA4(o0, wv, x0);
        FMA4(o1, wv, x1);
        FMA4(o2, wv, x2);
        FMA4(o3, wv, x3);
    }
    const float4 bv = *reinterpret_cast<const float4*>(&bias[cg]);
    const int row0 = blockIdx.x * 32 + r0;
    float4 oo[4] = {o0, o1, o2, o3};
#pragma unroll
    for (int r = 0; r < 4; ++r) {
        float4 o = oo[r];
        o.x = fmaxf(o.x + bv.x, 0.f); o.y = fmaxf(o.y + bv.y, 0.f);
        o.z = fmaxf(o.z + bv.z, 0.f); o.w = fmaxf(o.w + bv.w, 0.f);
        if (row0 + r < n)
            *reinterpret_cast<uint2*>(&out[(long long)(row0 + r) * 64 + (cg >> 1)]) =
                make_uint2(pack_bf2(o.x, o.y), pack_bf2(o.z, o.w));
    }
}

// ---------------- fused layer-3 gather(bf16) + pool partials ----------------
__device__ __forceinline__ int lower_bound_i(const int* __restrict__ a, int n, int key) {
    int lo = 0, hi = n;
    while (lo < hi) {
        int mid = (lo + hi) >> 1;
        if (a[mid] < key) lo = mid + 1; else hi = mid;
    }
    return lo;
}

__global__ __launch_bounds__(256) void gather_pool(const u32* __restrict__ H,
                                                   const int* __restrict__ rp,
                                                   const int2* __restrict__ cw,
                                                   const float* __restrict__ dinv,
                                                   const int* __restrict__ batch,
                                                   float* __restrict__ Spart, int n) {
    __shared__ float red[16 * 128];
    const int g = blockIdx.x / PARTS;
    const int part = blockIdx.x % PARTS;
    const int slot = threadIdx.x >> 4;     // 16 slots
    const int j = threadIdx.x & 15;        // feature octet 0..15
    const int start = lower_bound_i(batch, n, g);
    const int end = lower_bound_i(batch, n, g + 1);
    float a0[8], a1[8], a2[8], a3[8];
#pragma unroll
    for (int q = 0; q < 8; ++q) { a0[q] = 0.f; a1[q] = 0.f; a2[q] = 0.f; a3[q] = 0.f; }
    for (int node = start + part * 16 + slot; node < end; node += PARTS * 16) {
        const float di = dinv[node];
        const float c = di * di;
        const uint4 sv = *reinterpret_cast<const uint4*>(&H[(long long)node * 64 + j * 4]);
        BF_FMA8(a0, sv, c);
        int e = rp[node];
        const int eend = rp[node + 1];
        for (; e + 4 <= eend; e += 4) {
            const int2 c0 = cw[e], c1 = cw[e + 1], c2 = cw[e + 2], c3 = cw[e + 3];
            const uint4 h0 = *reinterpret_cast<const uint4*>(&H[(long long)c0.x * 64 + j * 4]);
            const uint4 h1 = *reinterpret_cast<const uint4*>(&H[(long long)c1.x * 64 + j * 4]);
            const uint4 h2 = *reinterpret_cast<const uint4*>(&H[(long long)c2.x * 64 + j * 4]);
            const uint4 h3 = *reinterpret_cast<const uint4*>(&H[(long long)c3.x * 64 + j * 4]);
            BF_FMA8(a0, h0, __int_as_float(c0.y));
            BF_FMA8(a1, h1, __int_as_float(c1.y));
            BF_FMA8(a2, h2, __int_as_float(c2.y));
            BF_FMA8(a3, h3, __int_as_float(c3.y));
        }
        if (e + 2 <= eend) {
            const int2 c0 = cw[e], c1 = cw[e + 1];
            const uint4 h0 = *reinterpret_cast<const uint4*>(&H[(long long)c0.x * 64 + j * 4]);
            const uint4 h1 = *reinterpret_cast<const uint4*>(&H[(long long)c1.x * 64 + j * 4]);
            BF_FMA8(a0, h0, __int_as_float(c0.y));
            BF_FMA8(a1, h1, __int_as_float(c1.y));
            e += 2;
        }
        if (e < eend) {
            const int2 c0 = cw[e];
            const uint4 h0 = *reinterpret_cast<const uint4*>(&H[(long long)c0.x * 64 + j * 4]);
            BF_FMA8(a0, h0, __int_as_float(c0.y));
        }
    }
#pragma unroll
    for (int q = 0; q < 8; ++q) a0[q] += a1[q] + a2[q] + a3[q];
    *reinterpret_cast<float4*>(&red[slot * 128 + j * 8]) =
        make_float4(a0[0], a0[1], a0[2], a0[3]);
    *reinterpret_cast<float4*>(&red[slot * 128 + j * 8 + 4]) =
        make_float4(a0[4], a0[5], a0[6], a0[7]);
    __syncthreads();
    const int t = threadIdx.x;
    if (t < 128) {
        float s = 0.f;
#pragma unroll
        for (int sl = 0; sl < 16; ++sl) s += red[sl * 128 + t];
        Spart[(long long)blockIdx.x * 128 + t] = s;
    }
}

// ---------------- final ----------------
__global__ __launch_bounds__(256) void final_k(const float* __restrict__ Spart,
                                               const int* __restrict__ batch,
                                               const float* __restrict__ W3,
                                               const float* __restrict__ b3,
                                               const float* __restrict__ Wlin,
                                               const float* __restrict__ blin,
                                               float* __restrict__ out, int n) {
    __shared__ float srow[128];
    __shared__ float prow[256];
    const int g = blockIdx.x;
    const int t = threadIdx.x;
    if (t < 128) {
        float s = 0.f;
#pragma unroll
        for (int p = 0; p < PARTS; ++p)
            s += Spart[(long long)(g * PARTS + p) * 128 + t];
        srow[t] = s;
    }
    __syncthreads();
    const int start = lower_bound_i(batch, n, g);
    const int end = lower_bound_i(batch, n, g + 1);
    const float cnt = (float)(end - start);
    const float inv = 1.0f / fmaxf(cnt, 1.0f);
    const float bscale = cnt * inv;
    float p = 0.f;
    for (int k = 0; k < 128; ++k) p += srow[k] * W3[k * 256 + t];
    prow[t] = p * inv + b3[t] * bscale;
    __syncthreads();
    if (t < 10) {
        float a = blin[t];
        for (int f = 0; f < 256; ++f) a += prow[f] * Wlin[f * 10 + t];
        out[g * 10 + t] = a;
    }
}

extern "C" void kernel_launch(void* const* d_in, const int* in_sizes, int n_in,
                              void* d_out, int out_size, void* d_ws, size_t ws_size,
                              hipStream_t stream) {
    const float* x     = (const float*)d_in[0];
    const int*   ei    = (const int*)d_in[1];
    const int*   batch = (const int*)d_in[2];
    const float* W1    = (const float*)d_in[3];
    const float* bc1   = (const float*)d_in[4];
    const float* W2    = (const float*)d_in[5];
    const float* bc2   = (const float*)d_in[6];
    const float* W3    = (const float*)d_in[7];
    const float* bc3   = (const float*)d_in[8];
    const float* Wlin  = (const float*)d_in[9];
    const float* blin  = (const float*)d_in[10];
    float* out = (float*)d_out;

    char* w = (char*)d_ws;
    int*   deg    = (int*)w;               w += 131072 * 4;
    int*   rp     = (int*)w;               w += 131072 * 4;
    int*   cursor = (int*)w;               w += 131072 * 4;
    int*   bsum   = (int*)w;               w += 256 * 4;
    float* dinv   = (float*)w;             w += 131072 * 4;
    int2*  cw     = (int2*)w;              w += (long long)NE * 8;
    u32*   Q      = (u32*)w;               w += (long long)NN * 64 * 2;   // h1 bf16
    u32*   P      = (u32*)w;               w += (long long)NN * 128 * 2;  // h2 bf16
    float* Spart  = (float*)w;             w += (long long)NG * PARTS * 128 * 4;

    const int nbScanA = (NN + 1023) / 1024;

    hipMemsetAsync(deg, 0, NN * sizeof(int), stream);
    deg_count<<<(NE + 255) / 256, 256, 0, stream>>>(ei + NE, deg, NE);
    scanA<<<nbScanA, 256, 0, stream>>>(deg, rp, bsum, NN);
    scanB<<<1, 128, 0, stream>>>(bsum, nbScanA);
    scanC<<<(NN + 256) / 256, 256, 0, stream>>>(rp, bsum, cursor, deg, dinv, NN, NE);
    fill_csr<<<(NE + 255) / 256, 256, 0, stream>>>(ei, dinv, cursor, cw, NE);

    gather_gemm_l1<<<(NN + 31) / 32, 256, 0, stream>>>(x, rp, cw, dinv, W1, bc1, Q, NN);
    gather_gemm_l2<<<(NN + 31) / 32, 256, 0, stream>>>(Q, rp, cw, dinv, W2, bc2, P, NN);
    gather_pool<<<NG * PARTS, 256, 0, stream>>>(P, rp, cw, dinv, batch, Spart, NN);
    final_k<<<NG, 256, 0, stream>>>(Spart, batch, W3, bc3, Wlin, blin, out, NN);
}